// Round 1
// baseline (130.307 us; speedup 1.0000x reference)
//
#include <hip/hip_runtime.h>
#include <stdint.h>

// Problem constants (fixed by reference)
#define NB 32    // batch
#define NC 64    // input channels
#define NH 64
#define NW 64
#define NO 512   // output channels
// K dims: 9 taps x 64 channels = 576

typedef __bf16 bf16x8 __attribute__((ext_vector_type(8)));
typedef short  s16x8  __attribute__((ext_vector_type(8)));
typedef float  f32x4  __attribute__((ext_vector_type(4)));

__device__ __forceinline__ uint16_t f2bf(float f) {
  uint32_t u = __builtin_bit_cast(uint32_t, f);
  u += 0x7fffu + ((u >> 16) & 1u);   // round-to-nearest-even
  return (uint16_t)(u >> 16);
}

// ---------------- kernel 1: build effective weights ----------------
// W_eff[o][c][p] = sum_s coef[o,s] * dict[idx[o,s]][c][p], p = kh*3+kw
// stored as Wl[p][o][c] bf16  (c contiguous -> 16B A-fragments)
__global__ void k_build_w(const float* __restrict__ dict,
                          const float* __restrict__ coef,
                          const int*   __restrict__ idx,
                          uint16_t*    __restrict__ Wl) {
  __shared__ float tmp[576];
  const int o = blockIdx.x;
  const int t = threadIdx.x;      // 0..575 ; c = t/9, p = t%9
  float v = 0.f;
#pragma unroll
  for (int s = 0; s < 4; ++s)
    v += coef[o * 4 + s] * dict[idx[o * 4 + s] * 576 + t];
  tmp[t] = v;
  __syncthreads();
  const int c = t & 63, p = t >> 6;   // 576 = 9*64
  Wl[(p * NO + o) * NC + c] = f2bf(tmp[c * 9 + p]);
}

// ---------------- kernel 2: x NCHW fp32 -> NHWC bf16 ----------------
__global__ void k_nhwc(const float* __restrict__ x, uint16_t* __restrict__ xh) {
  __shared__ float tile[64][65];    // +1 pad: conflict-free transpose
  const int bh = blockIdx.x;        // b*64 + h
  const int b = bh >> 6, h = bh & 63;
  const int t = threadIdx.x;        // 256
  const int w = t & 63;
#pragma unroll
  for (int c = (t >> 6); c < 64; c += 4)
    tile[c][w] = x[((size_t)(b * NC + c) * NH + h) * NW + w];
  __syncthreads();
  const int c = t & 63;
#pragma unroll
  for (int wi = (t >> 6); wi < 64; wi += 4)
    xh[((size_t)(b * NH + h) * NW + wi) * NC + c] = f2bf(tile[c][wi]);
}

// ---------------- kernel 3: implicit-GEMM conv ----------------
// out[b,o,h,w] = sum_{p,c} Wl[p][o][c] * xh[b][h+dh][w+dw][c] + bias[o]
// Block tile: 128 o  x  128 pixels (2 h-rows of one b).
// LDS: xs = x rows h0-1..h0+2, [4][64 w][64 c] bf16, swizzled, staged once.
//      as = Wl slice [128 o][64 c] bf16, swizzled, double-buffered per tap.
__global__ __launch_bounds__(256, 2) void k_conv(
    const uint16_t* __restrict__ xh,   // [B][H][W][C] bf16
    const uint16_t* __restrict__ Wl,   // [9][O][C] bf16
    const float*    __restrict__ bias,
    float*          __restrict__ out) {
  __shared__ __align__(16) uint16_t xs[4 * 64 * 64];      // 32 KB
  __shared__ __align__(16) uint16_t as[2 * 128 * 64];     // 32 KB

  const int t  = threadIdx.x;
  const int o0 = blockIdx.x * 128;
  const int gy = blockIdx.y;
  const int b  = gy >> 5;
  const int h0 = (gy & 31) * 2;

  // ---- stage x tile (rows h0-1 .. h0+2), swizzled writes ----
  {
#pragma unroll
    for (int r = 0; r < 4; ++r) {
      const int h = h0 - 1 + r;
      int4* dstrow = reinterpret_cast<int4*>(xs) + r * 512; // 512 x 16B per row
      if ((unsigned)h < 64u) {
        const int4* src = reinterpret_cast<const int4*>(
            xh + (size_t)((b * NH + h) * NW) * NC);
#pragma unroll
        for (int i = 0; i < 2; ++i) {
          const int s = t + i * 256;          // 16B slot
          const int wrow = s >> 3, cb = s & 7;
          dstrow[wrow * 8 + (cb ^ (wrow & 7))] = src[s];
        }
      } else {
#pragma unroll
        for (int i = 0; i < 2; ++i) {
          const int s = t + i * 256;
          dstrow[s] = int4{0, 0, 0, 0};
        }
      }
    }
  }

  // ---- A staging helper (one tap -> one buffer), swizzled writes ----
  auto stage_a = [&](int p, int bufsel) {
    const int4* src = reinterpret_cast<const int4*>(Wl + (size_t)(p * NO + o0) * NC);
    int4* dst = reinterpret_cast<int4*>(as) + bufsel * 1024;
#pragma unroll
    for (int i = 0; i < 4; ++i) {
      const int s = t + i * 256;
      const int orow = s >> 3, cb = s & 7;
      dst[orow * 8 + (cb ^ (orow & 7))] = src[s];
    }
  };

  const int lane = t & 63;
  const int wid  = t >> 6;      // 0..3
  const int wm   = wid >> 1;    // o sub-block (64 each)
  const int wn   = wid & 1;     // pixel sub-block (64 each) == h-row within pair
  const int l15  = lane & 15;
  const int g    = lane >> 4;   // k-group

  s16x8 zraw = {0, 0, 0, 0, 0, 0, 0, 0};
  const bf16x8 ZV = __builtin_bit_cast(bf16x8, zraw);

  f32x4 acc[4][4] = {};

  stage_a(0, 0);
  __syncthreads();

  int buf = 0;
  for (int p = 0; p < 9; ++p) {
    if (p < 8) stage_a(p + 1, buf ^ 1);

    const int dh = p / 3 - 1, dw = p % 3 - 1;
    const int rrow = wn + dh + 1;               // LDS x-row, always in [0,4)
    const uint16_t* asb = as + buf * 8192;

#pragma unroll
    for (int q = 0; q < 2; ++q) {               // two c-halves of 32
      bf16x8 af[4], bfr[4];
#pragma unroll
      for (int m = 0; m < 4; ++m) {
        const int orow = wm * 64 + m * 16 + l15;
        const int cb = (q * 4 + g) ^ (orow & 7);
        af[m] = __builtin_bit_cast(bf16x8,
            *reinterpret_cast<const s16x8*>(asb + orow * 64 + cb * 8));
      }
#pragma unroll
      for (int n = 0; n < 4; ++n) {
        const int w  = n * 16 + l15;
        const int wv = w + dw;
        const bool valid = (unsigned)wv < 64u;
        const int wc = valid ? wv : 0;
        const int row = rrow * 64 + wc;
        const int cb = (q * 4 + g) ^ (wc & 7);
        bf16x8 v = __builtin_bit_cast(bf16x8,
            *reinterpret_cast<const s16x8*>(xs + row * 64 + cb * 8));
        bfr[n] = valid ? v : ZV;
      }
#pragma unroll
      for (int m = 0; m < 4; ++m)
#pragma unroll
        for (int n = 0; n < 4; ++n)
          acc[m][n] = __builtin_amdgcn_mfma_f32_16x16x32_bf16(
              af[m], bfr[n], acc[m][n], 0, 0, 0);
    }
    __syncthreads();
    buf ^= 1;
  }

  // ---- epilogue: bias + store ----
  // D layout (verified): col = lane&15 (pixel), row = g*4 + reg (o)
  const int hpix = h0 + wn;
#pragma unroll
  for (int m = 0; m < 4; ++m) {
#pragma unroll
    for (int rr = 0; rr < 4; ++rr) {
      const int o = o0 + wm * 64 + m * 16 + g * 4 + rr;
      const float bv = bias[o];
      float* orow_p = out + ((size_t)(b * NO + o) * NH + hpix) * NW;
#pragma unroll
      for (int n = 0; n < 4; ++n)
        orow_p[n * 16 + l15] = acc[m][n][rr] + bv;
    }
  }
}

extern "C" void kernel_launch(void* const* d_in, const int* in_sizes, int n_in,
                              void* d_out, int out_size, void* d_ws, size_t ws_size,
                              hipStream_t stream) {
  const float* x    = (const float*)d_in[0];
  const float* dict = (const float*)d_in[1];
  const float* coef = (const float*)d_in[2];
  const float* bias = (const float*)d_in[3];
  const int*   idx  = (const int*)d_in[4];
  float* out = (float*)d_out;

  // workspace layout: xh (NHWC bf16) = 16 MiB at 0 ; Wl at +16 MiB (576 KiB)
  uint16_t* xh = (uint16_t*)d_ws;
  uint16_t* Wl = (uint16_t*)((char*)d_ws + (16u << 20));

  hipLaunchKernelGGL(k_build_w, dim3(512), dim3(576), 0, stream, dict, coef, idx, Wl);
  hipLaunchKernelGGL(k_nhwc, dim3(NB * NH), dim3(256), 0, stream, x, xh);
  hipLaunchKernelGGL(k_conv, dim3(NO / 128, NB * NH / 2), dim3(256), 0, stream,
                     xh, Wl, bias, out);
}

// Round 2
// 115.623 us; speedup vs baseline: 1.1270x; 1.1270x over previous
//
#include <hip/hip_runtime.h>
#include <stdint.h>

// Problem constants (fixed by reference)
#define NB 32    // batch
#define NC 64    // input channels
#define NH 64
#define NW 64
#define NO 512   // output channels
#define HP 66    // h-padded rows (1 zero row top+bottom)

typedef __bf16 bf16x8 __attribute__((ext_vector_type(8)));
typedef short  s16x8  __attribute__((ext_vector_type(8)));
typedef float  f32x4  __attribute__((ext_vector_type(4)));

__device__ __forceinline__ uint16_t f2bf(float f) {
  uint32_t u = __builtin_bit_cast(uint32_t, f);
  u += 0x7fffu + ((u >> 16) & 1u);   // round-to-nearest-even
  return (uint16_t)(u >> 16);
}

// async global->LDS, 16B per lane. LDS dest = wave-uniform base + lane*16.
__device__ __forceinline__ void gld16(const uint16_t* g, uint16_t* l) {
  __builtin_amdgcn_global_load_lds(
      (const __attribute__((address_space(1))) void*)(g),
      (__attribute__((address_space(3))) void*)(l), 16, 0, 0);
}

// ---------------- kernel 1: build effective weights (pre-swizzled) -------
// W_eff[o][c][p] = sum_s coef[o,s]*dict[idx[o,s]][c][p], p = kh*3+kw.
// Global layout matches the LDS tile EXACTLY (so staging is a linear DMA):
//   Wl[((p*NO + o)*8 + ((c>>3) ^ (o&7)))*8 + (c&7)]
__global__ void k_build_w(const float* __restrict__ dict,
                          const float* __restrict__ coef,
                          const int*   __restrict__ idx,
                          uint16_t*    __restrict__ Wl) {
  __shared__ float tmp[576];
  const int o = blockIdx.x;
  const int t = threadIdx.x;      // 0..575
  float v = 0.f;
#pragma unroll
  for (int s = 0; s < 4; ++s)
    v += coef[o * 4 + s] * dict[idx[o * 4 + s] * 576 + t];
  tmp[t] = v;
  __syncthreads();
  const int c = t & 63, p = t >> 6;   // 576 = 9*64
  const int sl = ((p * NO + o) * 8 + ((c >> 3) ^ (o & 7))) * 8 + (c & 7);
  Wl[sl] = f2bf(tmp[c * 9 + p]);
}

// ---------------- kernel 2: x NCHW fp32 -> padded swizzled NHWC bf16 -----
// xh[b][hp][w][c] with hp in [0,66), rows 0 and 65 all-zero; within a row,
// 16B chunk (c>>3) stored at chunk position ((c>>3) ^ (w&7)).
__global__ void k_nhwc(const float* __restrict__ x, uint16_t* __restrict__ xh) {
  const int bh = blockIdx.x;            // b*66 + hp
  const int b = bh / HP, hp = bh % HP;
  const int t = threadIdx.x;            // 256
  uint16_t* row = xh + (size_t)(b * HP + hp) * 4096;
  if (hp == 0 || hp == HP - 1) {        // zero pad rows
    int4* r4 = reinterpret_cast<int4*>(row);
    r4[t]       = int4{0, 0, 0, 0};
    r4[t + 256] = int4{0, 0, 0, 0};
    return;
  }
  __shared__ float tile[64][65];
  const int h = hp - 1;
  const int w = t & 63;
#pragma unroll
  for (int c = (t >> 6); c < 64; c += 4)
    tile[c][w] = x[((size_t)(b * NC + c) * NH + h) * NW + w];
  __syncthreads();
#pragma unroll
  for (int i = 0; i < 2; ++i) {
    const int s = t + i * 256;          // 512 slots of 16B
    const int w2 = s >> 3, cb = s & 7;
    uint32_t d[4];
#pragma unroll
    for (int j = 0; j < 4; ++j) {
      const uint32_t lo = f2bf(tile[cb * 8 + 2 * j][w2]);
      const uint32_t hi = f2bf(tile[cb * 8 + 2 * j + 1][w2]);
      d[j] = lo | (hi << 16);
    }
    reinterpret_cast<int4*>(row)[w2 * 8 + (cb ^ (w2 & 7))] =
        int4{(int)d[0], (int)d[1], (int)d[2], (int)d[3]};
  }
}

// ---------------- kernel 3: implicit-GEMM conv ----------------
// Block: 128 o x 128 pixels (2 h-rows of one b), 4 waves (2 o-sub x 2 h-sub).
// xs: x rows h0-1..h0+2, [4][66 w-slots][64 c] bf16 (w-halo slots zeroed),
//     staged ONCE via linear global_load_lds from padded/pre-swizzled xh.
// as: Wl slice [128 o][64 c] bf16, double-buffered per tap, linear DMA.
__global__ __launch_bounds__(256, 2) void k_conv(
    const uint16_t* __restrict__ xh,   // [NB][66][64][64] bf16, pre-swizzled
    const uint16_t* __restrict__ Wl,   // [9][512][64] bf16, pre-swizzled
    const float*    __restrict__ bias,
    float*          __restrict__ out) {
  __shared__ __align__(16) uint16_t xs[4 * 66 * 64];      // 33 KB
  __shared__ __align__(16) uint16_t as[2 * 128 * 64];     // 32 KB

  const int t = threadIdx.x;
  // XCD-chunked swizzle: XCD k gets contiguous gy in [k*128,(k+1)*128)
  const int flat = blockIdx.x;                 // 4096 blocks
  const int s    = (flat & 7) * 512 + (flat >> 3);
  const int ot   = s & 3;                      // o-tile
  const int gy   = s >> 2;                     // pixel tile (b, h-pair)
  const int o0 = ot * 128;
  const int b  = gy >> 5;
  const int h0 = (gy & 31) * 2;

  const int lane = t & 63;
  const int wid  = t >> 6;      // 0..3

  // ---- zero the w-halo slots (slot 0 and 65 of each of 4 rows) ----
  if (t < 64) {
    const int r = t >> 4, side = (t >> 3) & 1, k = t & 7;
    reinterpret_cast<int4*>(xs)[r * 528 + side * 520 + k] = int4{0, 0, 0, 0};
  }
  // ---- stage x interior: wave wid -> xs row wid, 8 linear 1KB chunks ----
  {
    const uint16_t* src = xh + (size_t)(b * HP + h0 + wid) * 4096;
    uint16_t* dst = xs + wid * 4224 + 64;      // skip w-halo slot 0
#pragma unroll
    for (int k = 0; k < 8; ++k)
      gld16(src + k * 512 + lane * 8, dst + k * 512);
  }
  // ---- stage A tap 0 ----
  {
    const uint16_t* src = Wl + o0 * 64;
#pragma unroll
    for (int j = 0; j < 4; ++j) {
      const int ch = wid * 4 + j;
      gld16(src + ch * 512 + lane * 8, as + ch * 512);
    }
  }

  const int wm  = wid >> 1;     // o sub-block (64 each)
  const int wn  = wid & 1;      // h-row within pair
  const int l15 = lane & 15;
  const int g   = lane >> 4;    // k-group

  f32x4 acc[4][4] = {};

  __syncthreads();

#pragma unroll
  for (int p = 0; p < 9; ++p) {
    const int buf = p & 1;
    if (p < 8) {   // stage A(p+1) into other buffer (issue before compute)
      const uint16_t* src = Wl + (p + 1) * 32768 + o0 * 64;
      uint16_t* dst = as + (buf ^ 1) * 8192;
#pragma unroll
      for (int j = 0; j < 4; ++j) {
        const int ch = wid * 4 + j;
        gld16(src + ch * 512 + lane * 8, dst + ch * 512);
      }
    }

    const int dh = p / 3 - 1, dw = p % 3 - 1;
    const int rbase = (wn + dh + 1) * 4224;    // xs row base (elems)
    const uint16_t* asb = as + buf * 8192;

#pragma unroll
    for (int q = 0; q < 2; ++q) {              // two c-halves of 32
      bf16x8 af[4], bfr[4];
#pragma unroll
      for (int m = 0; m < 4; ++m) {
        const int orow = wm * 64 + m * 16 + l15;
        const int cb = (q * 4 + g) ^ (orow & 7);
        af[m] = __builtin_bit_cast(bf16x8,
            *reinterpret_cast<const s16x8*>(asb + orow * 64 + cb * 8));
      }
#pragma unroll
      for (int n = 0; n < 4; ++n) {
        const int wv = n * 16 + l15 + dw;      // may be -1 or 64 -> zero slot
        const int cb = (q * 4 + g) ^ (wv & 7);
        bfr[n] = __builtin_bit_cast(bf16x8,
            *reinterpret_cast<const s16x8*>(xs + rbase + (wv + 1) * 64 + cb * 8));
      }
#pragma unroll
      for (int m = 0; m < 4; ++m)
#pragma unroll
        for (int n = 0; n < 4; ++n)
          acc[m][n] = __builtin_amdgcn_mfma_f32_16x16x32_bf16(
              af[m], bfr[n], acc[m][n], 0, 0, 0);
    }
    __syncthreads();
  }

  // ---- epilogue: bias + store ----
  // D layout (verified r1): col = lane&15 (pixel w), row = g*4 + reg (o)
  const int hpix = h0 + wn;
#pragma unroll
  for (int m = 0; m < 4; ++m) {
#pragma unroll
    for (int rr = 0; rr < 4; ++rr) {
      const int o = o0 + wm * 64 + m * 16 + g * 4 + rr;
      const float bv = bias[o];
      float* orow_p = out + ((size_t)(b * NO + o) * NH + hpix) * NW;
#pragma unroll
      for (int n = 0; n < 4; ++n)
        orow_p[n * 16 + l15] = acc[m][n][rr] + bv;
    }
  }
}

extern "C" void kernel_launch(void* const* d_in, const int* in_sizes, int n_in,
                              void* d_out, int out_size, void* d_ws, size_t ws_size,
                              hipStream_t stream) {
  const float* x    = (const float*)d_in[0];
  const float* dict = (const float*)d_in[1];
  const float* coef = (const float*)d_in[2];
  const float* bias = (const float*)d_in[3];
  const int*   idx  = (const int*)d_in[4];
  float* out = (float*)d_out;

  // workspace: xh padded/swizzled = 32*66*4096*2 B = 16.5 MiB at 0;
  //            Wl swizzled 576 KiB at +18 MiB
  uint16_t* xh = (uint16_t*)d_ws;
  uint16_t* Wl = (uint16_t*)((char*)d_ws + (18u << 20));

  hipLaunchKernelGGL(k_build_w, dim3(NO), dim3(576), 0, stream, dict, coef, idx, Wl);
  hipLaunchKernelGGL(k_nhwc, dim3(NB * HP), dim3(256), 0, stream, x, xh);
  hipLaunchKernelGGL(k_conv, dim3(4096), dim3(256), 0, stream, xh, Wl, bias, out);
}